// Round 7
// baseline (29324.643 us; speedup 1.0000x reference)
//
#include <hip/hip_runtime.h>
#include <stdint.h>
#include <math.h>

// ---------------------------------------------------------------------------
// ODE-LSTM on MI355X -- correctness round 4.
// Model: inputs f32 (confirmed R5), OUTPUTS f32 (per harness spec; R5/R6's
// identical layout-independent 0.98 error == bf16-written-to-f32-buffer).
// Expected arrays are bf16-quantized in the dataset => threshold 1.97e-2.
// B=4096, OBS=256, H=1024, OUT=256, T=20 (19 RK4 steps).
//
// Pipeline (validated math, unchanged since R5):
//   init: z = h, hs = h
//   19x4: t1 = tanh(z @ Wf1 + b1)            (MODE 0, t1 bf16)
//         k  = t1 @ Wf2 + b2 + RK4 update    (MODE 1)
//   gate = sigmoid([x|h] @ Wi + bi)          (MODE 2, bf16, after loop)
//   c_tilde GEMM (A=[x|z]) + c_new/h_new     (MODE 3, f32 outs)
//   out = h_new(f32) @ Wo + bo               (MODE 4, f32 out)
//
// d_out = 9,437,184 f32 = 37.75 MB: out @ elem [0,1M) | h_new @ [1M,5.25M)
//   | c_new @ [5.25M,9.44M).
// Plan A (ws >= 56 MB): zF/hsF f32 + t1/ks/gate bf16, all in ws.
// Plan C (ws >= 16 MB): zB/hsB bf16 in ws; t1 u16 @ d_out bytes [4,12)MB,
//   ks u16 @ [20,28)MB (dead before final writes); gate u16 in ws over dead
//   hsB after the loop.
// ---------------------------------------------------------------------------

__device__ __forceinline__ float bf2f(unsigned short u) {
  union { unsigned int i; float f; } x;
  x.i = ((unsigned int)u) << 16;
  return x.f;
}
__device__ __forceinline__ unsigned short f2bf(float f) {
  union { float f; unsigned int i; } x;
  x.f = f;
  unsigned int r = x.i + 0x7fffu + ((x.i >> 16) & 1u);  // RNE
  return (unsigned short)(r >> 16);
}

// C(MxN) = A(MxK row-major, two K-segments) @ W(KxN f32 row-major) + bias.
// AT1/AT2: segment dtype, 0 = f32, 1 = bf16(u16).  HS: h/z-state dtype MODE 1.
// 64x64 tile, BK=16, 256 threads, 4x4 microtile. grid: (N/64, M/64).
template <int MODE, int AT1, int AT2, int HS>
__global__ __launch_bounds__(256) void sgemm(
    const void* A1v, int K1, const void* A2v, int K2,
    const float* W, int N, const float* bias,
    const float* tgrid, int step, int stage,
    float* hsF, unsigned short* hsB,      // MODE 1: h-state (rw)
    float* zF, unsigned short* zB,        // MODE 1: z out
    unsigned short* ksumB,                // MODE 1: rw
    unsigned short* gateB,                // MODE 2 w, MODE 3 r
    const float* c_in,                    // MODE 3 r
    float* hnewF,                         // MODE 3 w (f32)
    float* cnewF,                         // MODE 3 w (f32)
    unsigned short* outU,                 // MODE 0 w (t1 bf16)
    float* outF) {                        // MODE 4 w (out f32)
  __shared__ float As[64][17];
  __shared__ float Ws[16][65];

  const int tid = threadIdx.x;
  const int tx = tid & 15, ty = tid >> 4;
  const int mBase = blockIdx.y * 64, nBase = blockIdx.x * 64;
  const int Kb = K1 + K2;

  float acc[4][4];
#pragma unroll
  for (int i = 0; i < 4; ++i)
#pragma unroll
    for (int j = 0; j < 4; ++j) acc[i][j] = 0.f;

  const int arow = tid >> 2, ak = (tid & 3) * 4;   // A staging map
  const int wn = tid & 63, wk4 = (tid >> 6) * 4;   // W staging map

  for (int k0 = 0; k0 < Kb; k0 += 16) {
    const bool seg1 = (k0 < K1);
    const void* aSeg = seg1 ? A1v : A2v;
    const int aLd = seg1 ? K1 : K2;
    const int ak0 = seg1 ? k0 : k0 - K1;
    const size_t aOff = (size_t)(mBase + arow) * aLd + ak0 + ak;
#pragma unroll
    for (int j = 0; j < 4; ++j) {
      float av;
      if (seg1)
        av = AT1 ? bf2f(((const unsigned short*)aSeg)[aOff + j])
                 : ((const float*)aSeg)[aOff + j];
      else
        av = AT2 ? bf2f(((const unsigned short*)aSeg)[aOff + j])
                 : ((const float*)aSeg)[aOff + j];
      As[arow][ak + j] = av;
    }
#pragma unroll
    for (int i = 0; i < 4; ++i)
      Ws[wk4 + i][wn] = W[(size_t)(k0 + wk4 + i) * N + nBase + wn];
    __syncthreads();

#pragma unroll
    for (int kk = 0; kk < 16; ++kk) {
      float a[4], b[4];
#pragma unroll
      for (int i = 0; i < 4; ++i) a[i] = As[ty * 4 + i][kk];
#pragma unroll
      for (int j = 0; j < 4; ++j) b[j] = Ws[kk][tx * 4 + j];
#pragma unroll
      for (int i = 0; i < 4; ++i)
#pragma unroll
        for (int j = 0; j < 4; ++j) acc[i][j] += a[i] * b[j];
    }
    __syncthreads();
  }

  // ---- fused epilogue ----
  const float dtv = (MODE == 1) ? (tgrid[step + 1] - tgrid[step]) : 0.f;

#pragma unroll
  for (int i = 0; i < 4; ++i) {
    const int row = mBase + ty * 4 + i;
#pragma unroll
    for (int j = 0; j < 4; ++j) {
      const int col = nBase + tx * 4 + j;
      const size_t idx = (size_t)row * N + col;
      const float v = acc[i][j] + bias[col];
      if (MODE == 0) {  // t1 = tanh(.)
        outU[idx] = f2bf(tanhf(v));
      } else if (MODE == 1) {  // RK4 stage; v = k_stage
        const float hv = HS ? bf2f(hsB[idx]) : hsF[idx];
        float znew;
        if (stage == 1) {
          ksumB[idx] = f2bf(v);
          znew = hv + 0.5f * dtv * v;
        } else if (stage == 2) {
          ksumB[idx] = f2bf(bf2f(ksumB[idx]) + 2.f * v);
          znew = hv + 0.5f * dtv * v;
        } else if (stage == 3) {
          ksumB[idx] = f2bf(bf2f(ksumB[idx]) + 2.f * v);
          znew = hv + dtv * v;
        } else {
          znew = hv + (dtv * (1.f / 6.f)) * (bf2f(ksumB[idx]) + v);
          if (HS) hsB[idx] = f2bf(znew); else hsF[idx] = znew;  // h <- h'
        }
        if (HS) zB[idx] = f2bf(znew); else zF[idx] = znew;
      } else if (MODE == 2) {  // gate = sigmoid(.)
        gateB[idx] = f2bf(1.f / (1.f + expf(-v)));
      } else if (MODE == 3) {  // c_tilde -> c_new, h_new (f32 outputs)
        const float ct = 1.f / (1.f + expf(-v));
        const float g = bf2f(gateB[idx]);
        const float cn = g * (c_in[idx] + ct);
        const float hn = g * tanhf(cn);
        hnewF[idx] = hn;
        cnewF[idx] = cn;
      } else {  // MODE 4: out = v (f32)
        outF[idx] = v;
      }
    }
  }
}

__global__ __launch_bounds__(256) void init_h_kernel(
    const float* h, float* hsF, float* zF,
    unsigned short* hsB, unsigned short* zB, int planA) {
  const int i = blockIdx.x * 256 + threadIdx.x;
  const float hv = h[i];
  if (planA) { hsF[i] = hv; zF[i] = hv; }
  else       { hsB[i] = f2bf(hv); zB[i] = f2bf(hv); }
}

extern "C" void kernel_launch(void* const* d_in, const int* in_sizes, int n_in,
                              void* d_out, int out_size, void* d_ws, size_t ws_size,
                              hipStream_t stream) {
  const float* x  = (const float*)d_in[0];   // 4096x256
  const float* h  = (const float*)d_in[1];   // 4096x1024
  const float* c  = (const float*)d_in[2];   // 4096x1024
  const float* t  = (const float*)d_in[3];   // 20
  const float* Wi = (const float*)d_in[4];   // 1280x1024
  const float* bi = (const float*)d_in[5];   // 1024
  const float* Wo = (const float*)d_in[6];   // 1024x256
  const float* bo = (const float*)d_in[7];   // 256
  const float* W1 = (const float*)d_in[8];   // 1024x1024
  const float* b1 = (const float*)d_in[9];   // 1024
  const float* W2 = (const float*)d_in[10];  // 1024x1024
  const float* b2 = (const float*)d_in[11];  // 1024

  const size_t MB = 1ull << 20;
  char* ws = (char*)d_ws;
  const int planA = (ws_size >= 56 * MB) ? 1 : 0;  // fixed across calls

  float* outpF = (float*)d_out;
  float* hnewF = outpF + 1048576;   // output 1: h_new (4096x1024 f32)
  float* cnewF = outpF + 5242880;   // output 2: c_new (4096x1024 f32)

  // Plan A scratch (all in ws, 56 MB)
  float*          zFA  = (float*)(ws);                    // [0, 16M)
  float*          hsFA = (float*)(ws + 16 * MB);          // [16M, 32M)
  unsigned short* t1A  = (unsigned short*)(ws + 32 * MB); // [32M, 40M)
  unsigned short* ksA  = (unsigned short*)(ws + 40 * MB); // [40M, 48M)
  unsigned short* gtA  = (unsigned short*)(ws + 48 * MB); // [48M, 56M)
  // Plan C scratch (16 MB ws + dead d_out byte ranges)
  unsigned short* zBC  = (unsigned short*)(ws);           // [0, 8M)
  unsigned short* hsBC = (unsigned short*)(ws + 8 * MB);  // [8M, 16M)
  unsigned short* t1C  = (unsigned short*)((char*)d_out + 4 * MB);   // [4,12)MB
  unsigned short* ksC  = (unsigned short*)((char*)d_out + 20 * MB);  // [20,28)MB
  unsigned short* gtC  = hsBC;  // gate over dead h-state (after the loop)

  unsigned short* t1 = planA ? t1A : t1C;
  unsigned short* ks = planA ? ksA : ksC;
  unsigned short* gt = planA ? gtA : gtC;

  init_h_kernel<<<16384, 256, 0, stream>>>(h, hsFA, zFA, hsBC, zBC, planA);

  const dim3 blk(256), g1024(16, 64), gOut(4, 64);

  // RK4: 19 steps x 4 stages
  for (int s = 0; s < 19; ++s) {
    for (int st = 1; st <= 4; ++st) {
      if (planA)
        sgemm<0, 0, 0, 0><<<g1024, blk, 0, stream>>>(
            zFA, 1024, nullptr, 0, W1, 1024, b1, nullptr, 0, 0,
            nullptr, nullptr, nullptr, nullptr, nullptr, nullptr, nullptr,
            nullptr, nullptr, t1, nullptr);
      else
        sgemm<0, 1, 0, 0><<<g1024, blk, 0, stream>>>(
            zBC, 1024, nullptr, 0, W1, 1024, b1, nullptr, 0, 0,
            nullptr, nullptr, nullptr, nullptr, nullptr, nullptr, nullptr,
            nullptr, nullptr, t1, nullptr);
      if (planA)
        sgemm<1, 1, 0, 0><<<g1024, blk, 0, stream>>>(
            t1, 1024, nullptr, 0, W2, 1024, b2, t, s, st,
            hsFA, nullptr, zFA, nullptr, ks, nullptr, nullptr,
            nullptr, nullptr, nullptr, nullptr);
      else
        sgemm<1, 1, 0, 1><<<g1024, blk, 0, stream>>>(
            t1, 1024, nullptr, 0, W2, 1024, b2, t, s, st,
            nullptr, hsBC, nullptr, zBC, ks, nullptr, nullptr,
            nullptr, nullptr, nullptr, nullptr);
    }
  }

  // gate = sigmoid([x|h] @ Wi + bi)  (after loop; Plan C reuses dead hsBC)
  sgemm<2, 0, 0, 0><<<g1024, blk, 0, stream>>>(
      x, 256, h, 1024, Wi, 1024, bi, nullptr, 0, 0,
      nullptr, nullptr, nullptr, nullptr, nullptr, gt, nullptr,
      nullptr, nullptr, nullptr, nullptr);

  // c_tilde (A=[x|z]) + fused c_new/h_new (f32 outputs)
  if (planA)
    sgemm<3, 0, 0, 0><<<g1024, blk, 0, stream>>>(
        x, 256, zFA, 1024, Wi, 1024, bi, nullptr, 0, 0,
        nullptr, nullptr, nullptr, nullptr, nullptr, gt, c,
        hnewF, cnewF, nullptr, nullptr);
  else
    sgemm<3, 0, 1, 0><<<g1024, blk, 0, stream>>>(
        x, 256, zBC, 1024, Wi, 1024, bi, nullptr, 0, 0,
        nullptr, nullptr, nullptr, nullptr, nullptr, gt, c,
        hnewF, cnewF, nullptr, nullptr);

  // out = h_new(f32) @ Wo + bo   (f32)
  sgemm<4, 0, 0, 0><<<gOut, blk, 0, stream>>>(
      hnewF, 1024, nullptr, 0, Wo, 256, bo, nullptr, 0, 0,
      nullptr, nullptr, nullptr, nullptr, nullptr, nullptr, nullptr,
      nullptr, nullptr, nullptr, outpF);
}

// Round 8
// 5674.909 us; speedup vs baseline: 5.1674x; 5.1674x over previous
//
#include <hip/hip_runtime.h>
#include <stdint.h>
#include <math.h>

// ---------------------------------------------------------------------------
// ODE-LSTM on MI355X -- MFMA round. Inputs f32, outputs f32 (confirmed R7).
// B=4096, OBS=256, H=1024, OUT=256, T=20 (19 RK4 steps).
//
//   1. transpose+cast weights f32 -> bf16 N x K (ws)
//   2. init: hs(f32, d_out overlay) = h, z(bf16, ws) = h
//   3. 19x4: t1 = tanh(z @ Wf1 + b1)          (MODE 0, bf16 MFMA)
//            k = t1 @ Wf2 + b2 + RK4 update   (MODE 1)
//   4. fused dual GEMM: gate=sigm([x|h]@Wi+bi), ct=sigm([x|z]@Wi+bi),
//      c_new = gate*(c+ct), h_new = gate*tanh(c_new)  -> d_out (f32)
//   5. out = h_new @ Wo + bo                  (MODE 4) -> d_out (f32)
//
// ws (15 MB): W1T[0,2M) W2T[2,4M) WiT[4,6.5M) WoT[6.5,7M) z[7,15M)
// d_out (37.75 MB f32) overlays during loop (all dead before final writes):
//   hs f32 @ bytes [0,16M) | ksum bf16 @ [16,24M) | t1 bf16 @ [24,32M)
// final: out f32 @ elems [0,1M) | h_new @ [1M,5.25M) | c_new @ [5.25M,9.44M)
// ---------------------------------------------------------------------------

typedef __attribute__((ext_vector_type(8))) short short8;
typedef __attribute__((ext_vector_type(4))) float float4v;

#define BM 128
#define BN 128
#define BK 64

__device__ __forceinline__ float bf2f(unsigned short u) {
  union { unsigned int i; float f; } x;
  x.i = ((unsigned int)u) << 16;
  return x.f;
}
__device__ __forceinline__ unsigned short f2bf(float f) {
  union { float f; unsigned int i; } x;
  x.f = f;
  unsigned int r = x.i + 0x7fffu + ((x.i >> 16) & 1u);  // RNE
  return (unsigned short)(r >> 16);
}
__device__ __forceinline__ void load16(const void* g, void* l) {
  __builtin_amdgcn_global_load_lds(
      (__attribute__((address_space(1))) void*)g,
      (__attribute__((address_space(3))) void*)l, 16, 0, 0);
}
__device__ __forceinline__ short8 packbf8(const float* p) {
  float4v lo = *(const float4v*)p, hi = *(const float4v*)(p + 4);
  short8 s;
  s[0] = (short)f2bf(lo[0]); s[1] = (short)f2bf(lo[1]);
  s[2] = (short)f2bf(lo[2]); s[3] = (short)f2bf(lo[3]);
  s[4] = (short)f2bf(hi[0]); s[5] = (short)f2bf(hi[1]);
  s[6] = (short)f2bf(hi[2]); s[7] = (short)f2bf(hi[3]);
  return s;
}

// C = A(MxK row-major) * Bt(NxK bf16 row-major)^T + bias, fused epilogue.
// ADT: 1 = A bf16 (global_load_lds path), 0 = A f32 (cvt in staging).
// grid (N/128, M/128), 256 threads (4 waves, 2x2), LDS XOR-swizzled chunks.
template <int MODE, int ADT>
__global__ __launch_bounds__(256, 1) void gemm_bt(
    const void* __restrict__ Av, const unsigned short* __restrict__ Bt,
    int N, int K, const float* __restrict__ bias,
    const float* __restrict__ tgrid, int step, int stage,
    float* __restrict__ hsF,
    unsigned short* __restrict__ ksumB,
    unsigned short* __restrict__ zB,
    unsigned short* __restrict__ t1B,
    float* __restrict__ outF) {
  // chunk c of AsV holds A[mBase + (c>>3)][k0 + 8*((c&7) ^ ((c>>3)&7))]
  __shared__ short8 AsV[1024];  // 128 x 64 bf16 = 16 KB
  __shared__ short8 BsV[1024];

  const int t = threadIdx.x;
  const int mBase = blockIdx.y * BM, nBase = blockIdx.x * BN;
  const int wave = t >> 6, lane = t & 63;
  const int wr = wave >> 1, wc = wave & 1;
  const int q = lane >> 4, m16 = lane & 15;

  float4v acc[4][4];
#pragma unroll
  for (int r = 0; r < 4; ++r)
#pragma unroll
    for (int c = 0; c < 4; ++c) acc[r][c] = (float4v){0.f, 0.f, 0.f, 0.f};

  const int r0 = t >> 3;               // staging row within 32-row group
  const int kcl = (t & 7) ^ (r0 & 7);  // swizzled k-chunk this thread fills
  const unsigned short* aU = (const unsigned short*)Av + (size_t)(mBase + r0) * K + kcl * 8;
  const float* aF = (const float*)Av + (size_t)(mBase + r0) * K + kcl * 8;
  const unsigned short* bG = Bt + (size_t)(nBase + r0) * K + kcl * 8;

  for (int k0 = 0; k0 < K; k0 += BK) {
#pragma unroll
    for (int i = 0; i < 4; ++i) {
      if (ADT == 1) {
        load16(aU + (size_t)(i * 32) * K + k0, &AsV[i * 256 + t]);
      } else {
        AsV[i * 256 + t] = packbf8(aF + (size_t)(i * 32) * K + k0);
      }
      load16(bG + (size_t)(i * 32) * K + k0, &BsV[i * 256 + t]);
    }
    __builtin_amdgcn_s_waitcnt(0);
    __syncthreads();

#pragma unroll
    for (int kk = 0; kk < 2; ++kk) {
      const int kc = kk * 4 + q;
      short8 af[4], bfr[4];
#pragma unroll
      for (int r = 0; r < 4; ++r) {
        const int arow = wr * 64 + r * 16 + m16;
        af[r] = AsV[arow * 8 + (kc ^ (arow & 7))];
        const int brow = wc * 64 + r * 16 + m16;
        bfr[r] = BsV[brow * 8 + (kc ^ (brow & 7))];
      }
#pragma unroll
      for (int r = 0; r < 4; ++r)
#pragma unroll
        for (int c = 0; c < 4; ++c)
          acc[r][c] = __builtin_amdgcn_mfma_f32_16x16x32_bf16(af[r], bfr[c],
                                                              acc[r][c], 0, 0, 0);
    }
    __syncthreads();
  }

  // ---- fused epilogue ----
  const float dtv = (MODE == 1) ? (tgrid[step + 1] - tgrid[step]) : 0.f;
  const int colBase = nBase + wc * 64 + m16;
  const int rowBase = mBase + wr * 64 + q * 4;
#pragma unroll
  for (int r = 0; r < 4; ++r) {
#pragma unroll
    for (int c = 0; c < 4; ++c) {
      const int col = colBase + c * 16;
      const float bv = bias[col];
#pragma unroll
      for (int e = 0; e < 4; ++e) {
        const int row = rowBase + r * 16 + e;
        const size_t idx = (size_t)row * N + col;
        const float v = acc[r][c][e] + bv;
        if (MODE == 0) {  // t1 = tanh(.)
          t1B[idx] = f2bf(tanhf(v));
        } else if (MODE == 1) {  // RK4 stage; v = k_stage
          const float hv = hsF[idx];
          float zn;
          if (stage == 1) {
            ksumB[idx] = f2bf(v);
            zn = hv + 0.5f * dtv * v;
          } else if (stage == 2) {
            ksumB[idx] = f2bf(bf2f(ksumB[idx]) + 2.f * v);
            zn = hv + 0.5f * dtv * v;
          } else if (stage == 3) {
            ksumB[idx] = f2bf(bf2f(ksumB[idx]) + 2.f * v);
            zn = hv + dtv * v;
          } else {
            zn = hv + (dtv * (1.f / 6.f)) * (bf2f(ksumB[idx]) + v);
            hsF[idx] = zn;
          }
          zB[idx] = f2bf(zn);
        } else {  // MODE 4: out = v (f32)
          outF[idx] = v;
        }
      }
    }
  }
}

// Fused gate + c_tilde dual GEMM: accG = [x|h] @ WiT^T, accC = [x|z] @ WiT^T;
// epilogue computes c_new / h_new directly. grid (8, 32).
__global__ __launch_bounds__(256, 1) void gemm_fused(
    const float* __restrict__ x, const float* __restrict__ h,
    const unsigned short* __restrict__ zB,
    const unsigned short* __restrict__ WiT,  // 1024 x 1280 bf16
    const float* __restrict__ bi, const float* __restrict__ c_in,
    float* __restrict__ hnewF, float* __restrict__ cnewF) {
  __shared__ short8 AsG[1024];
  __shared__ short8 AsC[1024];
  __shared__ short8 BsV[1024];

  const int t = threadIdx.x;
  const int mBase = blockIdx.y * BM, nBase = blockIdx.x * BN;
  const int wave = t >> 6, lane = t & 63;
  const int wr = wave >> 1, wc = wave & 1;
  const int q = lane >> 4, m16 = lane & 15;

  float4v accG[4][4], accC[4][4];
#pragma unroll
  for (int r = 0; r < 4; ++r)
#pragma unroll
    for (int c = 0; c < 4; ++c) {
      accG[r][c] = (float4v){0.f, 0.f, 0.f, 0.f};
      accC[r][c] = (float4v){0.f, 0.f, 0.f, 0.f};
    }

  const int r0 = t >> 3;
  const int kcl = (t & 7) ^ (r0 & 7);

  for (int k0 = 0; k0 < 1280; k0 += BK) {
    const bool isX = (k0 < 256);
#pragma unroll
    for (int i = 0; i < 4; ++i) {
      const int row = mBase + r0 + i * 32;
      const float* gp = isX ? (x + (size_t)row * 256 + k0 + kcl * 8)
                            : (h + (size_t)row * 1024 + (k0 - 256) + kcl * 8);
      const short8 sg = packbf8(gp);
      AsG[i * 256 + t] = sg;
      if (isX)
        AsC[i * 256 + t] = sg;
      else
        AsC[i * 256 + t] = *(const short8*)(zB + (size_t)row * 1024 + (k0 - 256) + kcl * 8);
      load16(WiT + (size_t)(nBase + r0 + i * 32) * 1280 + k0 + kcl * 8,
             &BsV[i * 256 + t]);
    }
    __builtin_amdgcn_s_waitcnt(0);
    __syncthreads();

#pragma unroll
    for (int kk = 0; kk < 2; ++kk) {
      const int kc = kk * 4 + q;
      short8 ag[4], ac[4], bfr[4];
#pragma unroll
      for (int r = 0; r < 4; ++r) {
        const int arow = wr * 64 + r * 16 + m16;
        ag[r] = AsG[arow * 8 + (kc ^ (arow & 7))];
        ac[r] = AsC[arow * 8 + (kc ^ (arow & 7))];
        const int brow = wc * 64 + r * 16 + m16;
        bfr[r] = BsV[brow * 8 + (kc ^ (brow & 7))];
      }
#pragma unroll
      for (int r = 0; r < 4; ++r)
#pragma unroll
        for (int c = 0; c < 4; ++c) {
          accG[r][c] = __builtin_amdgcn_mfma_f32_16x16x32_bf16(ag[r], bfr[c],
                                                               accG[r][c], 0, 0, 0);
          accC[r][c] = __builtin_amdgcn_mfma_f32_16x16x32_bf16(ac[r], bfr[c],
                                                               accC[r][c], 0, 0, 0);
        }
    }
    __syncthreads();
  }

  const int colBase = nBase + wc * 64 + m16;
  const int rowBase = mBase + wr * 64 + q * 4;
#pragma unroll
  for (int r = 0; r < 4; ++r) {
#pragma unroll
    for (int c = 0; c < 4; ++c) {
      const int col = colBase + c * 16;
      const float bv = bi[col];
#pragma unroll
      for (int e = 0; e < 4; ++e) {
        const int row = rowBase + r * 16 + e;
        const size_t idx = (size_t)row * 1024 + col;
        const float g = 1.f / (1.f + expf(-(accG[r][c][e] + bv)));
        const float ct = 1.f / (1.f + expf(-(accC[r][c][e] + bv)));
        const float cn = g * (c_in[idx] + ct);
        const float hn = g * tanhf(cn);
        hnewF[idx] = hn;
        cnewF[idx] = cn;
      }
    }
  }
}

// out[c][r] = bf16(in[r][c]); in f32 RxC. block (32,8), grid (C/32, R/32).
__global__ __launch_bounds__(256) void transpose_f32_bf16(
    const float* __restrict__ in, unsigned short* __restrict__ out,
    int R, int C) {
  __shared__ float tile[32][33];
  const int c0 = blockIdx.x * 32, r0 = blockIdx.y * 32;
  const int tx = threadIdx.x, ty = threadIdx.y;
#pragma unroll
  for (int i = 0; i < 32; i += 8)
    tile[ty + i][tx] = in[(size_t)(r0 + ty + i) * C + c0 + tx];
  __syncthreads();
#pragma unroll
  for (int i = 0; i < 32; i += 8)
    out[(size_t)(c0 + ty + i) * R + r0 + tx] = f2bf(tile[tx][ty + i]);
}

__global__ __launch_bounds__(256) void init_h_kernel(
    const float* __restrict__ h, float* __restrict__ hsF,
    unsigned short* __restrict__ zB) {
  const int i = blockIdx.x * 256 + threadIdx.x;
  const float hv = h[i];
  hsF[i] = hv;
  zB[i] = f2bf(hv);
}

extern "C" void kernel_launch(void* const* d_in, const int* in_sizes, int n_in,
                              void* d_out, int out_size, void* d_ws, size_t ws_size,
                              hipStream_t stream) {
  const float* x  = (const float*)d_in[0];   // 4096x256
  const float* h  = (const float*)d_in[1];   // 4096x1024
  const float* c  = (const float*)d_in[2];   // 4096x1024
  const float* t  = (const float*)d_in[3];   // 20
  const float* Wi = (const float*)d_in[4];   // 1280x1024
  const float* bi = (const float*)d_in[5];   // 1024
  const float* Wo = (const float*)d_in[6];   // 1024x256
  const float* bo = (const float*)d_in[7];   // 256
  const float* W1 = (const float*)d_in[8];   // 1024x1024
  const float* b1 = (const float*)d_in[9];   // 1024
  const float* W2 = (const float*)d_in[10];  // 1024x1024
  const float* b2 = (const float*)d_in[11];  // 1024

  const size_t MB = 1ull << 20;
  char* ws = (char*)d_ws;
  unsigned short* W1T = (unsigned short*)(ws);                       // [0,2M)
  unsigned short* W2T = (unsigned short*)(ws + 2 * MB);              // [2,4M)
  unsigned short* WiT = (unsigned short*)(ws + 4 * MB);              // [4,6.5M)
  unsigned short* WoT = (unsigned short*)(ws + 6 * MB + 512 * 1024); // [6.5,7M)
  unsigned short* zB  = (unsigned short*)(ws + 7 * MB);              // [7,15M)

  // d_out overlays (dead before final writes) + final outputs
  float*          outF  = (float*)d_out;
  float*          hnewF = outF + 1048576;                            // [4,20M) bytes
  float*          cnewF = outF + 5242880;                            // [20,36M)
  float*          hsF   = (float*)d_out;                             // [0,16M)
  unsigned short* ksum  = (unsigned short*)((char*)d_out + 16 * MB); // [16,24M)
  unsigned short* t1    = (unsigned short*)((char*)d_out + 24 * MB); // [24,32M)

  const dim3 tb(32, 8);
  transpose_f32_bf16<<<dim3(32, 32), tb, 0, stream>>>(W1, W1T, 1024, 1024);
  transpose_f32_bf16<<<dim3(32, 32), tb, 0, stream>>>(W2, W2T, 1024, 1024);
  transpose_f32_bf16<<<dim3(32, 40), tb, 0, stream>>>(Wi, WiT, 1280, 1024);
  transpose_f32_bf16<<<dim3(8, 32),  tb, 0, stream>>>(Wo, WoT, 1024, 256);

  init_h_kernel<<<16384, 256, 0, stream>>>(h, hsF, zB);

  const dim3 blk(256), g1024(8, 32), gOut(2, 32);

  // RK4: 19 steps x 4 stages (pure-bf16 MFMA GEMMs)
  for (int s = 0; s < 19; ++s) {
    for (int st = 1; st <= 4; ++st) {
      gemm_bt<0, 1><<<g1024, blk, 0, stream>>>(
          zB, W1T, 1024, 1024, b1, nullptr, 0, 0,
          nullptr, nullptr, nullptr, t1, nullptr);
      gemm_bt<1, 1><<<g1024, blk, 0, stream>>>(
          t1, W2T, 1024, 1024, b2, t, s, st,
          hsF, ksum, zB, nullptr, nullptr);
    }
  }

  // fused gate + c_tilde -> h_new, c_new (f32 outputs)
  gemm_fused<<<g1024, blk, 0, stream>>>(x, h, zB, WiT, bi, c, hnewF, cnewF);

  // out = h_new(f32) @ Wo + bo
  gemm_bt<4, 0><<<gOut, blk, 0, stream>>>(
      hnewF, WoT, 256, 1024, bo, nullptr, 0, 0,
      nullptr, nullptr, nullptr, nullptr, outF);
}